// Round 6
// baseline (287.210 us; speedup 1.0000x reference)
//
#include <hip/hip_runtime.h>

#define NN 100000
#define NC 16
#define NE 3200000
#define NLAYERS 4
#define ALPHA_C 0.5f

#define BSHIFT 8
#define NBUK 391            // ceil(NN / 256)
#define EPB 12544           // edges per block -> exactly 256 blocks
#define NBLK 256
#define CAP 9728            // LDS staging capacity per bucket (mean 8192, +17 sigma)

// ============ build phase (LDS atomics only) ============

__global__ __launch_bounds__(1024) void bucket_count(const int* __restrict__ dst,
                                                     int* __restrict__ counts) {
    __shared__ int h[NBUK];
    for (int i = threadIdx.x; i < NBUK; i += 1024) h[i] = 0;
    __syncthreads();
    int base = blockIdx.x * EPB;
    int nedge = min(EPB, NE - base);
    for (int i = threadIdx.x; i < nedge; i += 1024)
        atomicAdd(&h[dst[base + i] >> BSHIFT], 1);
    __syncthreads();
    for (int i = threadIdx.x; i < NBUK; i += 1024)
        counts[i * NBLK + blockIdx.x] = h[i];   // bucket-major for the scan
}

// Exclusive scan, 1024 elements per block (256 threads x 4 elems).
__global__ void scanA(int* __restrict__ data, int* __restrict__ blockSums, int n) {
    __shared__ int lds[256];
    int base = blockIdx.x * 1024 + threadIdx.x * 4;
    int v[4] = {0, 0, 0, 0};
#pragma unroll
    for (int i = 0; i < 4; ++i) { int idx = base + i; if (idx < n) v[i] = data[idx]; }
    int tsum = v[0] + v[1] + v[2] + v[3];
    lds[threadIdx.x] = tsum;
    __syncthreads();
    for (int off = 1; off < 256; off <<= 1) {
        int t = (threadIdx.x >= off) ? lds[threadIdx.x - off] : 0;
        __syncthreads();
        lds[threadIdx.x] += t;
        __syncthreads();
    }
    if (threadIdx.x == 255) blockSums[blockIdx.x] = lds[255];
    int run = lds[threadIdx.x] - tsum;
#pragma unroll
    for (int i = 0; i < 4; ++i) {
        int idx = base + i;
        if (idx < n) { int old = v[i]; data[idx] = run; run += old; }
    }
}

__global__ void scanB(int* __restrict__ blockSums, int nb) {
    __shared__ int lds[1024];
    int t = threadIdx.x;
    lds[t] = (t < nb) ? blockSums[t] : 0;
    __syncthreads();
    for (int off = 1; off < 1024; off <<= 1) {
        int v = (t >= off) ? lds[t - off] : 0;
        __syncthreads();
        lds[t] += v;
        __syncthreads();
    }
    if (t < nb) blockSums[t] = (t == 0) ? 0 : lds[t - 1];
}

__global__ void scanC(int* __restrict__ data, const int* __restrict__ blockSums, int n) {
    int idx = blockIdx.x * blockDim.x + threadIdx.x;
    if (idx < n) data[idx] += blockSums[idx >> 10];
    if (idx == 0) data[n] = NE;
}

// LDS-staged scatter: histogram -> LDS scan -> LDS placement (bucket-ordered)
// -> linear coalesced write-out. rec.x = src | (local_dst<<17), rec.y = w bits.
__global__ __launch_bounds__(1024) void bucket_scatter(
        const int* __restrict__ src, const int* __restrict__ dst,
        const float* __restrict__ ew, const float* __restrict__ W,
        const int* __restrict__ scanned, int2* __restrict__ recs) {
    __shared__ int2 lrec[EPB];               // 100352 B
    __shared__ unsigned short lbid[EPB];     // 25088 B
    __shared__ int h[NBUK];
    __shared__ int lbase[NBUK];
    __shared__ int delta[NBUK];
    __shared__ int sc[512];
    int t = threadIdx.x;
    int blk = blockIdx.x;
    for (int i = t; i < NBUK; i += 1024) h[i] = 0;
    __syncthreads();
    int base = blk * EPB;
    int nedge = min(EPB, NE - base);
    for (int i = t; i < nedge; i += 1024)
        atomicAdd(&h[dst[base + i] >> BSHIFT], 1);
    __syncthreads();
    // exclusive LDS scan of h -> lbase; delta = global base - local base
    if (t < 512) sc[t] = (t < NBUK) ? h[t] : 0;
    __syncthreads();
    for (int off = 1; off < 512; off <<= 1) {
        int v = (t >= off && t < 512) ? sc[t - off] : 0;
        __syncthreads();
        if (t < 512) sc[t] += v;
        __syncthreads();
    }
    if (t < NBUK) {
        int excl = sc[t] - h[t];
        lbase[t] = excl;
        delta[t] = scanned[t * NBLK + blk] - excl;
        h[t] = 0;
    }
    __syncthreads();
    // placement into LDS, bucket-ordered
    for (int i = t; i < nedge; i += 1024) {
        int e = base + i;
        int d = dst[e];
        int s = src[e];
        float w = ew[e] * W[s];
        int b = d >> BSHIFT;
        int r = atomicAdd(&h[b], 1);
        int slot = lbase[b] + r;
        lrec[slot] = make_int2(s | ((d & 255) << 17), __float_as_int(w));
        lbid[slot] = (unsigned short)b;
    }
    __syncthreads();
    // coalesced write-out: consecutive threads -> consecutive addresses per run
    for (int i = t; i < nedge; i += 1024) {
        int b = lbid[i];
        recs[i + delta[b]] = lrec[i];
    }
}

// One block (512 thr) per bucket: stage records in LDS, counting-sort the 256
// local dsts, write CSR offsets, rewrite records in place fully dst-sorted.
__global__ void bucket_sort(int2* __restrict__ recs, const int* __restrict__ scanned,
                            int* __restrict__ offsets) {
    __shared__ int2 lrec[CAP];
    __shared__ int hcnt[256];
    __shared__ int hscan[256];
    __shared__ int hexcl[256];
    int b = blockIdx.x;
    int t = threadIdx.x;
    int beg = scanned[b * NBLK];
    int end = (b == NBUK - 1) ? NE : scanned[(b + 1) * NBLK];
    int cnt = end - beg;
    if (t < 256) hcnt[t] = 0;
    __syncthreads();
    for (int i = t; i < cnt && i < CAP; i += 512) {
        int2 rv = recs[beg + i];
        lrec[i] = rv;
        atomicAdd(&hcnt[(rv.x >> 17) & 255], 1);
    }
    __syncthreads();
    if (t < 256) hscan[t] = hcnt[t];
    __syncthreads();
    for (int off = 1; off < 256; off <<= 1) {
        int v = 0;
        if (t >= off && t < 256) v = hscan[t - off];
        __syncthreads();
        if (t < 256) hscan[t] += v;
        __syncthreads();
    }
    if (t < 256) {
        hexcl[t] = hscan[t] - hcnt[t];
        int d = (b << BSHIFT) + t;
        if (d < NN) offsets[d] = beg + hexcl[t];
        hcnt[t] = 0;
    }
    if (b == NBUK - 1 && t == 0) offsets[NN] = NE;
    __syncthreads();
    for (int i = t; i < cnt && i < CAP; i += 512) {
        int2 rv = lrec[i];
        int ld = (rv.x >> 17) & 255;
        int r = atomicAdd(&hcnt[ld], 1);
        recs[beg + hexcl[ld] + r] = make_int2(rv.x & 0x1FFFF, rv.y);
    }
}

// ============ per-layer gather (contiguous CSR segment per node) ============
// 4 lanes per node; lane q owns classes [4q,4q+4). Fused deg^2-blend + rownorm.
// recs stream is nontemporal so the 6.4MB h table stays L2-resident.
__global__ void gather1(const float* __restrict__ h, const int2* __restrict__ recs,
                        const int* __restrict__ offsets, const float* __restrict__ degree,
                        float* __restrict__ hout) {
    int t = blockIdx.x * blockDim.x + threadIdx.x;
    int g = t >> 2;
    int q = t & 3;
    if (g >= NN) return;
    int q4 = q * 4;
    int beg = offsets[g];
    int end = offsets[g + 1];
    float4 acc = make_float4(0.f, 0.f, 0.f, 0.f);
    int i = beg;
    for (; i + 4 <= end; i += 4) {
        long long v0 = __builtin_nontemporal_load((const long long*)(recs + i));
        long long v1 = __builtin_nontemporal_load((const long long*)(recs + i + 1));
        long long v2 = __builtin_nontemporal_load((const long long*)(recs + i + 2));
        long long v3 = __builtin_nontemporal_load((const long long*)(recs + i + 3));
        int s0 = (int)v0, s1 = (int)v1, s2 = (int)v2, s3 = (int)v3;
        const float4 h0 = *reinterpret_cast<const float4*>(h + (size_t)s0 * NC + q4);
        const float4 h1 = *reinterpret_cast<const float4*>(h + (size_t)s1 * NC + q4);
        const float4 h2 = *reinterpret_cast<const float4*>(h + (size_t)s2 * NC + q4);
        const float4 h3 = *reinterpret_cast<const float4*>(h + (size_t)s3 * NC + q4);
        float w0 = __int_as_float((int)(v0 >> 32)), w1 = __int_as_float((int)(v1 >> 32));
        float w2 = __int_as_float((int)(v2 >> 32)), w3 = __int_as_float((int)(v3 >> 32));
        acc.x += h0.x * w0; acc.y += h0.y * w0; acc.z += h0.z * w0; acc.w += h0.w * w0;
        acc.x += h1.x * w1; acc.y += h1.y * w1; acc.z += h1.z * w1; acc.w += h1.w * w1;
        acc.x += h2.x * w2; acc.y += h2.y * w2; acc.z += h2.z * w2; acc.w += h2.w * w2;
        acc.x += h3.x * w3; acc.y += h3.y * w3; acc.z += h3.z * w3; acc.w += h3.w * w3;
    }
    for (; i < end; ++i) {
        long long v0 = __builtin_nontemporal_load((const long long*)(recs + i));
        int s0 = (int)v0;
        float w0 = __int_as_float((int)(v0 >> 32));
        const float4 h0 = *reinterpret_cast<const float4*>(h + (size_t)s0 * NC + q4);
        acc.x += h0.x * w0; acc.y += h0.y * w0; acc.z += h0.z * w0; acc.w += h0.w * w0;
    }
    float deg = degree[g];
    float d2 = deg * deg;
    const float4 hs = *reinterpret_cast<const float4*>(h + (size_t)g * NC + q4);
    float4 v;
    v.x = ALPHA_C * hs.x + (1.f - ALPHA_C) * d2 * acc.x;
    v.y = ALPHA_C * hs.y + (1.f - ALPHA_C) * d2 * acc.y;
    v.z = ALPHA_C * hs.z + (1.f - ALPHA_C) * d2 * acc.z;
    v.w = ALPHA_C * hs.w + (1.f - ALPHA_C) * d2 * acc.w;
    float s4 = v.x + v.y + v.z + v.w;
    s4 += __shfl_xor(s4, 1);
    s4 += __shfl_xor(s4, 2);
    float inv = 1.f / s4;
    v.x *= inv; v.y *= inv; v.z *= inv; v.w *= inv;
    *reinterpret_cast<float4*>(hout + (size_t)g * NC + q4) = v;
}

// ============ fallback (atomic-cursor CSR) ============

__global__ void hist_kernel(const int* __restrict__ dst, int* __restrict__ counts) {
    int e = blockIdx.x * blockDim.x + threadIdx.x;
    if (e < NE) atomicAdd(&counts[dst[e]], 1);
}

__global__ void scatter_sort(const int* __restrict__ src, const int* __restrict__ dst,
                             const float* __restrict__ ew, const float* __restrict__ W,
                             const int* __restrict__ offsets, int* __restrict__ cursor,
                             int2* __restrict__ sorted) {
    int e = blockIdx.x * blockDim.x + threadIdx.x;
    if (e >= NE) return;
    int d = dst[e];
    int s = src[e];
    int pos = offsets[d] + atomicAdd(&cursor[d], 1);
    float w = ew[e] * W[s];
    sorted[pos] = make_int2(s, __float_as_int(w));
}

// ============ launch ============

extern "C" void kernel_launch(void* const* d_in, const int* in_sizes, int n_in,
                              void* d_out, int out_size, void* d_ws, size_t ws_size,
                              hipStream_t stream)
{
    const float* x      = (const float*)d_in[0];
    const float* W      = (const float*)d_in[1];
    const float* ew     = (const float*)d_in[2];
    const float* degree = (const float*)d_in[3];
    const int*   eidx   = (const int*)d_in[4];
    const int* src = eidx;
    const int* dst = eidx + NE;
    float* out = (float*)d_out;

    const int node_blocks4 = (NN * 4 + 255) / 256;
    const int edge_blocks  = (NE + 255) / 256;

    const size_t recs_elems   = (size_t)NE;            // int2
    const size_t bufA_elems   = (size_t)NN * NC;       // float
    const size_t counts_elems = (size_t)NBUK * NBLK + 1;
    const size_t off_elems    = (size_t)NN + 1;
    const size_t need = recs_elems * 8 + bufA_elems * 4 + counts_elems * 4
                      + off_elems * 4 + 1024 * 4 + 64;

    if (ws_size >= need) {
        int2*  recs      = (int2*)d_ws;
        float* bufA      = (float*)(recs + recs_elems);
        int*   counts    = (int*)(bufA + bufA_elems);
        int*   offsets   = counts + counts_elems;
        int*   blockSums = offsets + off_elems;

        bucket_count<<<NBLK, 1024, 0, stream>>>(dst, counts);
        const int n_scan = NBUK * NBLK;                 // 100096
        const int NB = (n_scan + 1023) / 1024;          // 98
        scanA<<<NB, 256, 0, stream>>>(counts, blockSums, n_scan);
        scanB<<<1, 1024, 0, stream>>>(blockSums, NB);
        scanC<<<(n_scan + 255) / 256, 256, 0, stream>>>(counts, blockSums, n_scan);
        bucket_scatter<<<NBLK, 1024, 0, stream>>>(src, dst, ew, W, counts, recs);
        bucket_sort<<<NBUK, 512, 0, stream>>>(recs, counts, offsets);

        const float* hin = x;
        float* houts[NLAYERS] = {bufA, out, bufA, out};
        for (int l = 0; l < NLAYERS; ++l) {
            gather1<<<node_blocks4, 256, 0, stream>>>(hin, recs, offsets, degree, houts[l]);
            hin = houts[l];
        }
        return;
    }

    // -------- fallback: single CSR with cursor atomics --------
    {
        int2*  sorted    = (int2*)d_ws;
        float* bufA      = (float*)(sorted + NE);
        int*   offsets   = (int*)(bufA + bufA_elems);
        int*   cursor    = offsets + (NN + 1);
        int*   blockSums = cursor + NN;

        hipMemsetAsync(offsets, 0, (size_t)(2 * NN + 1) * sizeof(int), stream);
        hist_kernel<<<edge_blocks, 256, 0, stream>>>(dst, offsets);
        const int NB = (NN + 1023) / 1024;
        scanA<<<NB, 256, 0, stream>>>(offsets, blockSums, NN);
        scanB<<<1, 1024, 0, stream>>>(blockSums, NB);
        scanC<<<(NN + 255) / 256, 256, 0, stream>>>(offsets, blockSums, NN);
        scatter_sort<<<edge_blocks, 256, 0, stream>>>(src, dst, ew, W, offsets, cursor, sorted);

        const float* hin = x;
        float* houts[NLAYERS] = {bufA, out, bufA, out};
        for (int l = 0; l < NLAYERS; ++l) {
            gather1<<<node_blocks4, 256, 0, stream>>>(hin, sorted, offsets, degree, houts[l]);
            hin = houts[l];
        }
    }
}

// Round 7
// 271.231 us; speedup vs baseline: 1.0589x; 1.0589x over previous
//
#include <hip/hip_runtime.h>

#define NN 100000
#define NC 16
#define NE 3200000
#define NLAYERS 4
#define ALPHA_C 0.5f

#define BSHIFT 8
#define NBUK 391            // ceil(NN / 256)
#define EPB 12544           // edges per block -> exactly 256 blocks
#define NBLK 256
#define CAP 9728            // LDS staging capacity per bucket (mean 8192, +17 sigma)

typedef __attribute__((ext_vector_type(4))) _Float16 half4;

// ============ build phase (LDS atomics only) ============

__global__ __launch_bounds__(1024) void bucket_count(const int* __restrict__ dst,
                                                     int* __restrict__ counts) {
    __shared__ int h[NBUK];
    for (int i = threadIdx.x; i < NBUK; i += 1024) h[i] = 0;
    __syncthreads();
    int base = blockIdx.x * EPB;
    int nedge = min(EPB, NE - base);
    for (int i = threadIdx.x; i < nedge; i += 1024)
        atomicAdd(&h[dst[base + i] >> BSHIFT], 1);
    __syncthreads();
    for (int i = threadIdx.x; i < NBUK; i += 1024)
        counts[i * NBLK + blockIdx.x] = h[i];   // bucket-major for the scan
}

// Exclusive scan, 1024 elements per block (256 threads x 4 elems).
__global__ void scanA(int* __restrict__ data, int* __restrict__ blockSums, int n) {
    __shared__ int lds[256];
    int base = blockIdx.x * 1024 + threadIdx.x * 4;
    int v[4] = {0, 0, 0, 0};
#pragma unroll
    for (int i = 0; i < 4; ++i) { int idx = base + i; if (idx < n) v[i] = data[idx]; }
    int tsum = v[0] + v[1] + v[2] + v[3];
    lds[threadIdx.x] = tsum;
    __syncthreads();
    for (int off = 1; off < 256; off <<= 1) {
        int t = (threadIdx.x >= off) ? lds[threadIdx.x - off] : 0;
        __syncthreads();
        lds[threadIdx.x] += t;
        __syncthreads();
    }
    if (threadIdx.x == 255) blockSums[blockIdx.x] = lds[255];
    int run = lds[threadIdx.x] - tsum;
#pragma unroll
    for (int i = 0; i < 4; ++i) {
        int idx = base + i;
        if (idx < n) { int old = v[i]; data[idx] = run; run += old; }
    }
}

__global__ void scanB(int* __restrict__ blockSums, int nb) {
    __shared__ int lds[1024];
    int t = threadIdx.x;
    lds[t] = (t < nb) ? blockSums[t] : 0;
    __syncthreads();
    for (int off = 1; off < 1024; off <<= 1) {
        int v = (t >= off) ? lds[t - off] : 0;
        __syncthreads();
        lds[t] += v;
        __syncthreads();
    }
    if (t < nb) blockSums[t] = (t == 0) ? 0 : lds[t - 1];
}

__global__ void scanC(int* __restrict__ data, const int* __restrict__ blockSums, int n) {
    int idx = blockIdx.x * blockDim.x + threadIdx.x;
    if (idx < n) data[idx] += blockSums[idx >> 10];
    if (idx == 0) data[n] = NE;
}

// LDS-staged scatter: histogram -> LDS scan -> LDS placement (bucket-ordered)
// -> linear coalesced write-out. rec.x = src | (local_dst<<17), rec.y = w bits.
__global__ __launch_bounds__(1024) void bucket_scatter(
        const int* __restrict__ src, const int* __restrict__ dst,
        const float* __restrict__ ew, const float* __restrict__ W,
        const int* __restrict__ scanned, int2* __restrict__ recs) {
    __shared__ int2 lrec[EPB];               // 100352 B
    __shared__ unsigned short lbid[EPB];     // 25088 B
    __shared__ int h[NBUK];
    __shared__ int lbase[NBUK];
    __shared__ int delta[NBUK];
    __shared__ int sc[512];
    int t = threadIdx.x;
    int blk = blockIdx.x;
    for (int i = t; i < NBUK; i += 1024) h[i] = 0;
    __syncthreads();
    int base = blk * EPB;
    int nedge = min(EPB, NE - base);
    for (int i = t; i < nedge; i += 1024)
        atomicAdd(&h[dst[base + i] >> BSHIFT], 1);
    __syncthreads();
    // exclusive LDS scan of h -> lbase; delta = global base - local base
    if (t < 512) sc[t] = (t < NBUK) ? h[t] : 0;
    __syncthreads();
    for (int off = 1; off < 512; off <<= 1) {
        int v = (t >= off && t < 512) ? sc[t - off] : 0;
        __syncthreads();
        if (t < 512) sc[t] += v;
        __syncthreads();
    }
    if (t < NBUK) {
        int excl = sc[t] - h[t];
        lbase[t] = excl;
        delta[t] = scanned[t * NBLK + blk] - excl;
        h[t] = 0;
    }
    __syncthreads();
    // placement into LDS, bucket-ordered
    for (int i = t; i < nedge; i += 1024) {
        int e = base + i;
        int d = dst[e];
        int s = src[e];
        float w = ew[e] * W[s];
        int b = d >> BSHIFT;
        int r = atomicAdd(&h[b], 1);
        int slot = lbase[b] + r;
        lrec[slot] = make_int2(s | ((d & 255) << 17), __float_as_int(w));
        lbid[slot] = (unsigned short)b;
    }
    __syncthreads();
    // coalesced write-out: consecutive threads -> consecutive addresses per run
    for (int i = t; i < nedge; i += 1024) {
        int b = lbid[i];
        recs[i + delta[b]] = lrec[i];
    }
}

// One block (512 thr) per bucket: stage records in LDS, counting-sort the 256
// local dsts, write CSR offsets, rewrite records in place fully dst-sorted.
__global__ void bucket_sort(int2* __restrict__ recs, const int* __restrict__ scanned,
                            int* __restrict__ offsets) {
    __shared__ int2 lrec[CAP];
    __shared__ int hcnt[256];
    __shared__ int hscan[256];
    __shared__ int hexcl[256];
    int b = blockIdx.x;
    int t = threadIdx.x;
    int beg = scanned[b * NBLK];
    int end = (b == NBUK - 1) ? NE : scanned[(b + 1) * NBLK];
    int cnt = end - beg;
    if (t < 256) hcnt[t] = 0;
    __syncthreads();
    for (int i = t; i < cnt && i < CAP; i += 512) {
        int2 rv = recs[beg + i];
        lrec[i] = rv;
        atomicAdd(&hcnt[(rv.x >> 17) & 255], 1);
    }
    __syncthreads();
    if (t < 256) hscan[t] = hcnt[t];
    __syncthreads();
    for (int off = 1; off < 256; off <<= 1) {
        int v = 0;
        if (t >= off && t < 256) v = hscan[t - off];
        __syncthreads();
        if (t < 256) hscan[t] += v;
        __syncthreads();
    }
    if (t < 256) {
        hexcl[t] = hscan[t] - hcnt[t];
        int d = (b << BSHIFT) + t;
        if (d < NN) offsets[d] = beg + hexcl[t];
        hcnt[t] = 0;
    }
    if (b == NBUK - 1 && t == 0) offsets[NN] = NE;
    __syncthreads();
    for (int i = t; i < cnt && i < CAP; i += 512) {
        int2 rv = lrec[i];
        int ld = (rv.x >> 17) & 255;
        int r = atomicAdd(&hcnt[ld], 1);
        recs[beg + hexcl[ld] + r] = make_int2(rv.x & 0x1FFFF, rv.y);
    }
}

// ============ fp32 -> fp16 conversion (once) ============
__global__ void f32_to_f16(const float* __restrict__ in, _Float16* __restrict__ out) {
    int i = blockIdx.x * blockDim.x + threadIdx.x;
    int base = i * 4;
    if (base < NN * NC) {
        float4 v = *reinterpret_cast<const float4*>(in + base);
        half4 o;
        o.x = (_Float16)v.x; o.y = (_Float16)v.y;
        o.z = (_Float16)v.z; o.w = (_Float16)v.w;
        *reinterpret_cast<half4*>(out + base) = o;
    }
}

// ============ per-layer gather (fp16 h table, fp32 math) ============
// 4 lanes per node; lane q owns classes [4q,4q+4). Fused deg^2-blend + rownorm.
// h table is 3.2MB fp16 -> fits each XCD's 4MB L2; recs stream is nontemporal.
template<bool LAST>
__global__ void gather_f16(const _Float16* __restrict__ h, const int2* __restrict__ recs,
                           const int* __restrict__ offsets, const float* __restrict__ degree,
                           _Float16* __restrict__ hout16, float* __restrict__ hout32) {
    int t = blockIdx.x * blockDim.x + threadIdx.x;
    int g = t >> 2;
    int q = t & 3;
    if (g >= NN) return;
    int q4 = q * 4;
    int beg = offsets[g];
    int end = offsets[g + 1];
    float4 acc = make_float4(0.f, 0.f, 0.f, 0.f);
    int i = beg;
    for (; i + 4 <= end; i += 4) {
        long long v0 = __builtin_nontemporal_load((const long long*)(recs + i));
        long long v1 = __builtin_nontemporal_load((const long long*)(recs + i + 1));
        long long v2 = __builtin_nontemporal_load((const long long*)(recs + i + 2));
        long long v3 = __builtin_nontemporal_load((const long long*)(recs + i + 3));
        int s0 = (int)v0, s1 = (int)v1, s2 = (int)v2, s3 = (int)v3;
        const half4 h0 = *reinterpret_cast<const half4*>(h + (size_t)s0 * NC + q4);
        const half4 h1 = *reinterpret_cast<const half4*>(h + (size_t)s1 * NC + q4);
        const half4 h2 = *reinterpret_cast<const half4*>(h + (size_t)s2 * NC + q4);
        const half4 h3 = *reinterpret_cast<const half4*>(h + (size_t)s3 * NC + q4);
        float w0 = __int_as_float((int)(v0 >> 32)), w1 = __int_as_float((int)(v1 >> 32));
        float w2 = __int_as_float((int)(v2 >> 32)), w3 = __int_as_float((int)(v3 >> 32));
        acc.x += (float)h0.x * w0; acc.y += (float)h0.y * w0;
        acc.z += (float)h0.z * w0; acc.w += (float)h0.w * w0;
        acc.x += (float)h1.x * w1; acc.y += (float)h1.y * w1;
        acc.z += (float)h1.z * w1; acc.w += (float)h1.w * w1;
        acc.x += (float)h2.x * w2; acc.y += (float)h2.y * w2;
        acc.z += (float)h2.z * w2; acc.w += (float)h2.w * w2;
        acc.x += (float)h3.x * w3; acc.y += (float)h3.y * w3;
        acc.z += (float)h3.z * w3; acc.w += (float)h3.w * w3;
    }
    for (; i < end; ++i) {
        long long v0 = __builtin_nontemporal_load((const long long*)(recs + i));
        int s0 = (int)v0;
        float w0 = __int_as_float((int)(v0 >> 32));
        const half4 h0 = *reinterpret_cast<const half4*>(h + (size_t)s0 * NC + q4);
        acc.x += (float)h0.x * w0; acc.y += (float)h0.y * w0;
        acc.z += (float)h0.z * w0; acc.w += (float)h0.w * w0;
    }
    float deg = degree[g];
    float d2 = deg * deg;
    const half4 hsv = *reinterpret_cast<const half4*>(h + (size_t)g * NC + q4);
    float4 v;
    v.x = ALPHA_C * (float)hsv.x + (1.f - ALPHA_C) * d2 * acc.x;
    v.y = ALPHA_C * (float)hsv.y + (1.f - ALPHA_C) * d2 * acc.y;
    v.z = ALPHA_C * (float)hsv.z + (1.f - ALPHA_C) * d2 * acc.z;
    v.w = ALPHA_C * (float)hsv.w + (1.f - ALPHA_C) * d2 * acc.w;
    float s4 = v.x + v.y + v.z + v.w;
    s4 += __shfl_xor(s4, 1);
    s4 += __shfl_xor(s4, 2);
    float inv = 1.f / s4;
    v.x *= inv; v.y *= inv; v.z *= inv; v.w *= inv;
    if (LAST) {
        *reinterpret_cast<float4*>(hout32 + (size_t)g * NC + q4) = v;
    } else {
        half4 o;
        o.x = (_Float16)v.x; o.y = (_Float16)v.y;
        o.z = (_Float16)v.z; o.w = (_Float16)v.w;
        *reinterpret_cast<half4*>(hout16 + (size_t)g * NC + q4) = o;
    }
}

// ============ fallback (atomic-cursor CSR, fp32 gather) ============

__global__ void hist_kernel(const int* __restrict__ dst, int* __restrict__ counts) {
    int e = blockIdx.x * blockDim.x + threadIdx.x;
    if (e < NE) atomicAdd(&counts[dst[e]], 1);
}

__global__ void scatter_sort(const int* __restrict__ src, const int* __restrict__ dst,
                             const float* __restrict__ ew, const float* __restrict__ W,
                             const int* __restrict__ offsets, int* __restrict__ cursor,
                             int2* __restrict__ sorted) {
    int e = blockIdx.x * blockDim.x + threadIdx.x;
    if (e >= NE) return;
    int d = dst[e];
    int s = src[e];
    int pos = offsets[d] + atomicAdd(&cursor[d], 1);
    float w = ew[e] * W[s];
    sorted[pos] = make_int2(s, __float_as_int(w));
}

__global__ void gather1(const float* __restrict__ h, const int2* __restrict__ recs,
                        const int* __restrict__ offsets, const float* __restrict__ degree,
                        float* __restrict__ hout) {
    int t = blockIdx.x * blockDim.x + threadIdx.x;
    int g = t >> 2;
    int q = t & 3;
    if (g >= NN) return;
    int q4 = q * 4;
    int beg = offsets[g];
    int end = offsets[g + 1];
    float4 acc = make_float4(0.f, 0.f, 0.f, 0.f);
    for (int i = beg; i < end; ++i) {
        int2 r0 = recs[i];
        float w0 = __int_as_float(r0.y);
        const float4 h0 = *reinterpret_cast<const float4*>(h + (size_t)(r0.x & 0x1FFFF) * NC + q4);
        acc.x += h0.x * w0; acc.y += h0.y * w0; acc.z += h0.z * w0; acc.w += h0.w * w0;
    }
    float deg = degree[g];
    float d2 = deg * deg;
    const float4 hs = *reinterpret_cast<const float4*>(h + (size_t)g * NC + q4);
    float4 v;
    v.x = ALPHA_C * hs.x + (1.f - ALPHA_C) * d2 * acc.x;
    v.y = ALPHA_C * hs.y + (1.f - ALPHA_C) * d2 * acc.y;
    v.z = ALPHA_C * hs.z + (1.f - ALPHA_C) * d2 * acc.z;
    v.w = ALPHA_C * hs.w + (1.f - ALPHA_C) * d2 * acc.w;
    float s4 = v.x + v.y + v.z + v.w;
    s4 += __shfl_xor(s4, 1);
    s4 += __shfl_xor(s4, 2);
    float inv = 1.f / s4;
    v.x *= inv; v.y *= inv; v.z *= inv; v.w *= inv;
    *reinterpret_cast<float4*>(hout + (size_t)g * NC + q4) = v;
}

// ============ launch ============

extern "C" void kernel_launch(void* const* d_in, const int* in_sizes, int n_in,
                              void* d_out, int out_size, void* d_ws, size_t ws_size,
                              hipStream_t stream)
{
    const float* x      = (const float*)d_in[0];
    const float* W      = (const float*)d_in[1];
    const float* ew     = (const float*)d_in[2];
    const float* degree = (const float*)d_in[3];
    const int*   eidx   = (const int*)d_in[4];
    const int* src = eidx;
    const int* dst = eidx + NE;
    float* out = (float*)d_out;

    const int node_blocks4 = (NN * 4 + 255) / 256;
    const int edge_blocks  = (NE + 255) / 256;

    const size_t recs_elems   = (size_t)NE;            // int2
    const size_t h16_elems    = (size_t)NN * NC;       // _Float16, x2 buffers
    const size_t counts_elems = (size_t)NBUK * NBLK + 1;
    const size_t off_elems    = (size_t)NN + 1;
    const size_t need = recs_elems * 8 + h16_elems * 2 * 2 + counts_elems * 4
                      + off_elems * 4 + 1024 * 4 + 64;

    if (ws_size >= need) {
        int2*      recs      = (int2*)d_ws;
        _Float16*  h16a      = (_Float16*)(recs + recs_elems);
        _Float16*  h16b      = h16a + h16_elems;
        int*       counts    = (int*)(h16b + h16_elems);
        int*       offsets   = counts + counts_elems;
        int*       blockSums = offsets + off_elems;

        bucket_count<<<NBLK, 1024, 0, stream>>>(dst, counts);
        const int n_scan = NBUK * NBLK;                 // 100096
        const int NB = (n_scan + 1023) / 1024;          // 98
        scanA<<<NB, 256, 0, stream>>>(counts, blockSums, n_scan);
        scanB<<<1, 1024, 0, stream>>>(blockSums, NB);
        scanC<<<(n_scan + 255) / 256, 256, 0, stream>>>(counts, blockSums, n_scan);
        bucket_scatter<<<NBLK, 1024, 0, stream>>>(src, dst, ew, W, counts, recs);
        bucket_sort<<<NBUK, 512, 0, stream>>>(recs, counts, offsets);

        f32_to_f16<<<(NN * NC / 4 + 255) / 256, 256, 0, stream>>>(x, h16a);
        gather_f16<false><<<node_blocks4, 256, 0, stream>>>(h16a, recs, offsets, degree, h16b, nullptr);
        gather_f16<false><<<node_blocks4, 256, 0, stream>>>(h16b, recs, offsets, degree, h16a, nullptr);
        gather_f16<false><<<node_blocks4, 256, 0, stream>>>(h16a, recs, offsets, degree, h16b, nullptr);
        gather_f16<true ><<<node_blocks4, 256, 0, stream>>>(h16b, recs, offsets, degree, nullptr, out);
        return;
    }

    // -------- fallback: single CSR with cursor atomics, fp32 gather --------
    {
        const size_t bufA_elems = (size_t)NN * NC;
        int2*  sorted    = (int2*)d_ws;
        float* bufA      = (float*)(sorted + NE);
        int*   offsets   = (int*)(bufA + bufA_elems);
        int*   cursor    = offsets + (NN + 1);
        int*   blockSums = cursor + NN;

        hipMemsetAsync(offsets, 0, (size_t)(2 * NN + 1) * sizeof(int), stream);
        hist_kernel<<<edge_blocks, 256, 0, stream>>>(dst, offsets);
        const int NB = (NN + 1023) / 1024;
        scanA<<<NB, 256, 0, stream>>>(offsets, blockSums, NN);
        scanB<<<1, 1024, 0, stream>>>(blockSums, NB);
        scanC<<<(NN + 255) / 256, 256, 0, stream>>>(offsets, blockSums, NN);
        scatter_sort<<<edge_blocks, 256, 0, stream>>>(src, dst, ew, W, offsets, cursor, sorted);

        const float* hin = x;
        float* houts[NLAYERS] = {bufA, out, bufA, out};
        for (int l = 0; l < NLAYERS; ++l) {
            gather1<<<node_blocks4, 256, 0, stream>>>(hin, sorted, offsets, degree, houts[l]);
            hin = houts[l];
        }
    }
}

// Round 8
// 246.245 us; speedup vs baseline: 1.1664x; 1.1015x over previous
//
#include <hip/hip_runtime.h>

#define NN 100000
#define NC 16
#define NE 3200000
#define NLAYERS 4
#define ALPHA_C 0.5f

#define BSHIFT 8
#define NBUK 391            // ceil(NN / 256)
#define EPB 12544           // edges per block -> exactly 256 blocks
#define NBLK 256
#define CAP 9728            // LDS staging capacity per bucket (mean 8192, +17 sigma)

typedef __attribute__((ext_vector_type(4))) _Float16 half4;

// ============ build phase (LDS atomics only) ============

__global__ __launch_bounds__(1024) void bucket_count(const int* __restrict__ dst,
                                                     int* __restrict__ counts) {
    __shared__ int h[NBUK];
    for (int i = threadIdx.x; i < NBUK; i += 1024) h[i] = 0;
    __syncthreads();
    int base = blockIdx.x * EPB;
    int nedge = min(EPB, NE - base);
    for (int i = threadIdx.x; i < nedge; i += 1024)
        atomicAdd(&h[dst[base + i] >> BSHIFT], 1);
    __syncthreads();
    for (int i = threadIdx.x; i < NBUK; i += 1024)
        counts[i * NBLK + blockIdx.x] = h[i];   // bucket-major for the scan
}

// Exclusive scan, 1024 elements per block (256 threads x 4 elems).
__global__ void scanA(int* __restrict__ data, int* __restrict__ blockSums, int n) {
    __shared__ int lds[256];
    int base = blockIdx.x * 1024 + threadIdx.x * 4;
    int v[4] = {0, 0, 0, 0};
#pragma unroll
    for (int i = 0; i < 4; ++i) { int idx = base + i; if (idx < n) v[i] = data[idx]; }
    int tsum = v[0] + v[1] + v[2] + v[3];
    lds[threadIdx.x] = tsum;
    __syncthreads();
    for (int off = 1; off < 256; off <<= 1) {
        int t = (threadIdx.x >= off) ? lds[threadIdx.x - off] : 0;
        __syncthreads();
        lds[threadIdx.x] += t;
        __syncthreads();
    }
    if (threadIdx.x == 255) blockSums[blockIdx.x] = lds[255];
    int run = lds[threadIdx.x] - tsum;
#pragma unroll
    for (int i = 0; i < 4; ++i) {
        int idx = base + i;
        if (idx < n) { int old = v[i]; data[idx] = run; run += old; }
    }
}

__global__ void scanB(int* __restrict__ blockSums, int nb) {
    __shared__ int lds[1024];
    int t = threadIdx.x;
    lds[t] = (t < nb) ? blockSums[t] : 0;
    __syncthreads();
    for (int off = 1; off < 1024; off <<= 1) {
        int v = (t >= off) ? lds[t - off] : 0;
        __syncthreads();
        lds[t] += v;
        __syncthreads();
    }
    if (t < nb) blockSums[t] = (t == 0) ? 0 : lds[t - 1];
}

__global__ void scanC(int* __restrict__ data, const int* __restrict__ blockSums, int n) {
    int idx = blockIdx.x * blockDim.x + threadIdx.x;
    if (idx < n) data[idx] += blockSums[idx >> 10];
    if (idx == 0) data[n] = NE;
}

// LDS-staged scatter: histogram -> LDS scan -> LDS placement (bucket-ordered)
// -> linear coalesced write-out. rec.x = src | (local_dst<<17), rec.y = w bits.
__global__ __launch_bounds__(1024) void bucket_scatter(
        const int* __restrict__ src, const int* __restrict__ dst,
        const float* __restrict__ ew, const float* __restrict__ W,
        const int* __restrict__ scanned, int2* __restrict__ recs) {
    __shared__ int2 lrec[EPB];               // 100352 B
    __shared__ unsigned short lbid[EPB];     // 25088 B
    __shared__ int h[NBUK];
    __shared__ int lbase[NBUK];
    __shared__ int delta[NBUK];
    __shared__ int sc[512];
    int t = threadIdx.x;
    int blk = blockIdx.x;
    for (int i = t; i < NBUK; i += 1024) h[i] = 0;
    __syncthreads();
    int base = blk * EPB;
    int nedge = min(EPB, NE - base);
    for (int i = t; i < nedge; i += 1024)
        atomicAdd(&h[dst[base + i] >> BSHIFT], 1);
    __syncthreads();
    // exclusive LDS scan of h -> lbase; delta = global base - local base
    if (t < 512) sc[t] = (t < NBUK) ? h[t] : 0;
    __syncthreads();
    for (int off = 1; off < 512; off <<= 1) {
        int v = (t >= off && t < 512) ? sc[t - off] : 0;
        __syncthreads();
        if (t < 512) sc[t] += v;
        __syncthreads();
    }
    if (t < NBUK) {
        int excl = sc[t] - h[t];
        lbase[t] = excl;
        delta[t] = scanned[t * NBLK + blk] - excl;
        h[t] = 0;
    }
    __syncthreads();
    // placement into LDS, bucket-ordered
    for (int i = t; i < nedge; i += 1024) {
        int e = base + i;
        int d = dst[e];
        int s = src[e];
        float w = ew[e] * W[s];
        int b = d >> BSHIFT;
        int r = atomicAdd(&h[b], 1);
        int slot = lbase[b] + r;
        lrec[slot] = make_int2(s | ((d & 255) << 17), __float_as_int(w));
        lbid[slot] = (unsigned short)b;
    }
    __syncthreads();
    // coalesced write-out: consecutive threads -> consecutive addresses per run
    for (int i = t; i < nedge; i += 1024) {
        int b = lbid[i];
        recs[i + delta[b]] = lrec[i];
    }
}

// One block (512 thr) per bucket: stage records in LDS, counting-sort the 256
// local dsts, write CSR offsets, rewrite records in place fully dst-sorted.
__global__ void bucket_sort(int2* __restrict__ recs, const int* __restrict__ scanned,
                            int* __restrict__ offsets) {
    __shared__ int2 lrec[CAP];
    __shared__ int hcnt[256];
    __shared__ int hscan[256];
    __shared__ int hexcl[256];
    int b = blockIdx.x;
    int t = threadIdx.x;
    int beg = scanned[b * NBLK];
    int end = (b == NBUK - 1) ? NE : scanned[(b + 1) * NBLK];
    int cnt = end - beg;
    if (t < 256) hcnt[t] = 0;
    __syncthreads();
    for (int i = t; i < cnt && i < CAP; i += 512) {
        int2 rv = recs[beg + i];
        lrec[i] = rv;
        atomicAdd(&hcnt[(rv.x >> 17) & 255], 1);
    }
    __syncthreads();
    if (t < 256) hscan[t] = hcnt[t];
    __syncthreads();
    for (int off = 1; off < 256; off <<= 1) {
        int v = 0;
        if (t >= off && t < 256) v = hscan[t - off];
        __syncthreads();
        if (t < 256) hscan[t] += v;
        __syncthreads();
    }
    if (t < 256) {
        hexcl[t] = hscan[t] - hcnt[t];
        int d = (b << BSHIFT) + t;
        if (d < NN) offsets[d] = beg + hexcl[t];
        hcnt[t] = 0;
    }
    if (b == NBUK - 1 && t == 0) offsets[NN] = NE;
    __syncthreads();
    for (int i = t; i < cnt && i < CAP; i += 512) {
        int2 rv = lrec[i];
        int ld = (rv.x >> 17) & 255;
        int r = atomicAdd(&hcnt[ld], 1);
        recs[beg + hexcl[ld] + r] = make_int2(rv.x & 0x1FFFF, rv.y);
    }
}

// ============ fp32 -> fp16 conversion (once) ============
__global__ void f32_to_f16(const float* __restrict__ in, _Float16* __restrict__ out) {
    int i = blockIdx.x * blockDim.x + threadIdx.x;
    int base = i * 4;
    if (base < NN * NC) {
        float4 v = *reinterpret_cast<const float4*>(in + base);
        half4 o;
        o.x = (_Float16)v.x; o.y = (_Float16)v.y;
        o.z = (_Float16)v.z; o.w = (_Float16)v.w;
        *reinterpret_cast<half4*>(out + base) = o;
    }
}

// ============ per-layer gather (fp16 h table, 8 lanes/node) ============
// sub = t&7: q = sub&3 owns classes [4q,4q+4); half = sub>>2 owns an edge
// half-range. Halves merged via shfl_xor(4); rownorm via shfl_xor(1,2).
template<bool LAST>
__global__ void gather_f16(const _Float16* __restrict__ h, const int2* __restrict__ recs,
                           const int* __restrict__ offsets, const float* __restrict__ degree,
                           _Float16* __restrict__ hout16, float* __restrict__ hout32) {
    int t = blockIdx.x * blockDim.x + threadIdx.x;
    int g = t >> 3;
    int sub = t & 7;
    int q = sub & 3;
    int half = sub >> 2;
    if (g >= NN) return;
    int q4 = q * 4;
    int beg = offsets[g];
    int end = offsets[g + 1];
    int mid = beg + ((end - beg + 1) >> 1);
    int lo = half ? mid : beg;
    int hi = half ? end : mid;
    float4 acc = make_float4(0.f, 0.f, 0.f, 0.f);
    int i = lo;
    for (; i + 4 <= hi; i += 4) {
        long long v0 = __builtin_nontemporal_load((const long long*)(recs + i));
        long long v1 = __builtin_nontemporal_load((const long long*)(recs + i + 1));
        long long v2 = __builtin_nontemporal_load((const long long*)(recs + i + 2));
        long long v3 = __builtin_nontemporal_load((const long long*)(recs + i + 3));
        int s0 = (int)v0, s1 = (int)v1, s2 = (int)v2, s3 = (int)v3;
        const half4 h0 = *reinterpret_cast<const half4*>(h + (size_t)s0 * NC + q4);
        const half4 h1 = *reinterpret_cast<const half4*>(h + (size_t)s1 * NC + q4);
        const half4 h2 = *reinterpret_cast<const half4*>(h + (size_t)s2 * NC + q4);
        const half4 h3 = *reinterpret_cast<const half4*>(h + (size_t)s3 * NC + q4);
        float w0 = __int_as_float((int)(v0 >> 32)), w1 = __int_as_float((int)(v1 >> 32));
        float w2 = __int_as_float((int)(v2 >> 32)), w3 = __int_as_float((int)(v3 >> 32));
        acc.x += (float)h0.x * w0; acc.y += (float)h0.y * w0;
        acc.z += (float)h0.z * w0; acc.w += (float)h0.w * w0;
        acc.x += (float)h1.x * w1; acc.y += (float)h1.y * w1;
        acc.z += (float)h1.z * w1; acc.w += (float)h1.w * w1;
        acc.x += (float)h2.x * w2; acc.y += (float)h2.y * w2;
        acc.z += (float)h2.z * w2; acc.w += (float)h2.w * w2;
        acc.x += (float)h3.x * w3; acc.y += (float)h3.y * w3;
        acc.z += (float)h3.z * w3; acc.w += (float)h3.w * w3;
    }
    for (; i < hi; ++i) {
        long long v0 = __builtin_nontemporal_load((const long long*)(recs + i));
        int s0 = (int)v0;
        float w0 = __int_as_float((int)(v0 >> 32));
        const half4 h0 = *reinterpret_cast<const half4*>(h + (size_t)s0 * NC + q4);
        acc.x += (float)h0.x * w0; acc.y += (float)h0.y * w0;
        acc.z += (float)h0.z * w0; acc.w += (float)h0.w * w0;
    }
    // merge the two edge-halves (lanes differ only in bit 2)
    acc.x += __shfl_xor(acc.x, 4);
    acc.y += __shfl_xor(acc.y, 4);
    acc.z += __shfl_xor(acc.z, 4);
    acc.w += __shfl_xor(acc.w, 4);
    float deg = degree[g];
    float d2 = deg * deg;
    const half4 hsv = *reinterpret_cast<const half4*>(h + (size_t)g * NC + q4);
    float4 v;
    v.x = ALPHA_C * (float)hsv.x + (1.f - ALPHA_C) * d2 * acc.x;
    v.y = ALPHA_C * (float)hsv.y + (1.f - ALPHA_C) * d2 * acc.y;
    v.z = ALPHA_C * (float)hsv.z + (1.f - ALPHA_C) * d2 * acc.z;
    v.w = ALPHA_C * (float)hsv.w + (1.f - ALPHA_C) * d2 * acc.w;
    float s4 = v.x + v.y + v.z + v.w;
    s4 += __shfl_xor(s4, 1);
    s4 += __shfl_xor(s4, 2);
    float inv = 1.f / s4;
    v.x *= inv; v.y *= inv; v.z *= inv; v.w *= inv;
    if (half == 0) {
        if (LAST) {
            *reinterpret_cast<float4*>(hout32 + (size_t)g * NC + q4) = v;
        } else {
            half4 o;
            o.x = (_Float16)v.x; o.y = (_Float16)v.y;
            o.z = (_Float16)v.z; o.w = (_Float16)v.w;
            *reinterpret_cast<half4*>(hout16 + (size_t)g * NC + q4) = o;
        }
    }
}

// ============ fallback (atomic-cursor CSR, fp32 gather) ============

__global__ void hist_kernel(const int* __restrict__ dst, int* __restrict__ counts) {
    int e = blockIdx.x * blockDim.x + threadIdx.x;
    if (e < NE) atomicAdd(&counts[dst[e]], 1);
}

__global__ void scatter_sort(const int* __restrict__ src, const int* __restrict__ dst,
                             const float* __restrict__ ew, const float* __restrict__ W,
                             const int* __restrict__ offsets, int* __restrict__ cursor,
                             int2* __restrict__ sorted) {
    int e = blockIdx.x * blockDim.x + threadIdx.x;
    if (e >= NE) return;
    int d = dst[e];
    int s = src[e];
    int pos = offsets[d] + atomicAdd(&cursor[d], 1);
    float w = ew[e] * W[s];
    sorted[pos] = make_int2(s, __float_as_int(w));
}

__global__ void gather1(const float* __restrict__ h, const int2* __restrict__ recs,
                        const int* __restrict__ offsets, const float* __restrict__ degree,
                        float* __restrict__ hout) {
    int t = blockIdx.x * blockDim.x + threadIdx.x;
    int g = t >> 2;
    int q = t & 3;
    if (g >= NN) return;
    int q4 = q * 4;
    int beg = offsets[g];
    int end = offsets[g + 1];
    float4 acc = make_float4(0.f, 0.f, 0.f, 0.f);
    for (int i = beg; i < end; ++i) {
        int2 r0 = recs[i];
        float w0 = __int_as_float(r0.y);
        const float4 h0 = *reinterpret_cast<const float4*>(h + (size_t)(r0.x & 0x1FFFF) * NC + q4);
        acc.x += h0.x * w0; acc.y += h0.y * w0; acc.z += h0.z * w0; acc.w += h0.w * w0;
    }
    float deg = degree[g];
    float d2 = deg * deg;
    const float4 hs = *reinterpret_cast<const float4*>(h + (size_t)g * NC + q4);
    float4 v;
    v.x = ALPHA_C * hs.x + (1.f - ALPHA_C) * d2 * acc.x;
    v.y = ALPHA_C * hs.y + (1.f - ALPHA_C) * d2 * acc.y;
    v.z = ALPHA_C * hs.z + (1.f - ALPHA_C) * d2 * acc.z;
    v.w = ALPHA_C * hs.w + (1.f - ALPHA_C) * d2 * acc.w;
    float s4 = v.x + v.y + v.z + v.w;
    s4 += __shfl_xor(s4, 1);
    s4 += __shfl_xor(s4, 2);
    float inv = 1.f / s4;
    v.x *= inv; v.y *= inv; v.z *= inv; v.w *= inv;
    *reinterpret_cast<float4*>(hout + (size_t)g * NC + q4) = v;
}

// ============ launch ============

extern "C" void kernel_launch(void* const* d_in, const int* in_sizes, int n_in,
                              void* d_out, int out_size, void* d_ws, size_t ws_size,
                              hipStream_t stream)
{
    const float* x      = (const float*)d_in[0];
    const float* W      = (const float*)d_in[1];
    const float* ew     = (const float*)d_in[2];
    const float* degree = (const float*)d_in[3];
    const int*   eidx   = (const int*)d_in[4];
    const int* src = eidx;
    const int* dst = eidx + NE;
    float* out = (float*)d_out;

    const int node_blocks8 = (NN * 8 + 255) / 256;     // 8 lanes per node
    const int node_blocks4 = (NN * 4 + 255) / 256;
    const int edge_blocks  = (NE + 255) / 256;

    const size_t recs_elems   = (size_t)NE;            // int2
    const size_t h16_elems    = (size_t)NN * NC;       // _Float16, x2 buffers
    const size_t counts_elems = (size_t)NBUK * NBLK + 1;
    const size_t off_elems    = (size_t)NN + 1;
    const size_t need = recs_elems * 8 + h16_elems * 2 * 2 + counts_elems * 4
                      + off_elems * 4 + 1024 * 4 + 64;

    if (ws_size >= need) {
        int2*      recs      = (int2*)d_ws;
        _Float16*  h16a      = (_Float16*)(recs + recs_elems);
        _Float16*  h16b      = h16a + h16_elems;
        int*       counts    = (int*)(h16b + h16_elems);
        int*       offsets   = counts + counts_elems;
        int*       blockSums = offsets + off_elems;

        bucket_count<<<NBLK, 1024, 0, stream>>>(dst, counts);
        const int n_scan = NBUK * NBLK;                 // 100096
        const int NB = (n_scan + 1023) / 1024;          // 98
        scanA<<<NB, 256, 0, stream>>>(counts, blockSums, n_scan);
        scanB<<<1, 1024, 0, stream>>>(blockSums, NB);
        scanC<<<(n_scan + 255) / 256, 256, 0, stream>>>(counts, blockSums, n_scan);
        bucket_scatter<<<NBLK, 1024, 0, stream>>>(src, dst, ew, W, counts, recs);
        bucket_sort<<<NBUK, 512, 0, stream>>>(recs, counts, offsets);

        f32_to_f16<<<(NN * NC / 4 + 255) / 256, 256, 0, stream>>>(x, h16a);
        gather_f16<false><<<node_blocks8, 256, 0, stream>>>(h16a, recs, offsets, degree, h16b, nullptr);
        gather_f16<false><<<node_blocks8, 256, 0, stream>>>(h16b, recs, offsets, degree, h16a, nullptr);
        gather_f16<false><<<node_blocks8, 256, 0, stream>>>(h16a, recs, offsets, degree, h16b, nullptr);
        gather_f16<true ><<<node_blocks8, 256, 0, stream>>>(h16b, recs, offsets, degree, nullptr, out);
        return;
    }

    // -------- fallback: single CSR with cursor atomics, fp32 gather --------
    {
        const size_t bufA_elems = (size_t)NN * NC;
        int2*  sorted    = (int2*)d_ws;
        float* bufA      = (float*)(sorted + NE);
        int*   offsets   = (int*)(bufA + bufA_elems);
        int*   cursor    = offsets + (NN + 1);
        int*   blockSums = cursor + NN;

        hipMemsetAsync(offsets, 0, (size_t)(2 * NN + 1) * sizeof(int), stream);
        hist_kernel<<<edge_blocks, 256, 0, stream>>>(dst, offsets);
        const int NB = (NN + 1023) / 1024;
        scanA<<<NB, 256, 0, stream>>>(offsets, blockSums, NN);
        scanB<<<1, 1024, 0, stream>>>(blockSums, NB);
        scanC<<<(NN + 255) / 256, 256, 0, stream>>>(offsets, blockSums, NN);
        scatter_sort<<<edge_blocks, 256, 0, stream>>>(src, dst, ew, W, offsets, cursor, sorted);

        const float* hin = x;
        float* houts[NLAYERS] = {bufA, out, bufA, out};
        for (int l = 0; l < NLAYERS; ++l) {
            gather1<<<node_blocks4, 256, 0, stream>>>(hin, sorted, offsets, degree, houts[l]);
            hin = houts[l];
        }
    }
}